// Round 5
// baseline (393.387 us; speedup 1.0000x reference)
//
#include <hip/hip_runtime.h>
#include <hip/hip_cooperative_groups.h>
#include <math.h>

namespace cg = cooperative_groups;

#define FEAT 128
#define BSHIFT 6            // 64 nodes per bucket: long scatter runs + 1-pass agg
#define BNODES 64
#define CAP2 2048           // records per sort chunk in mega kernel (16 KB LDS)
#define NBUCK_MAX 1024      // N <= 65536 -> nbuck <= 1024
#define EPB 4096
#define MTHREADS 512

__device__ __forceinline__ float edge_weight(float d, float scale, float fw, float fb) {
    // scale already includes +1e-6
    float t = fmaxf(d / scale, 0.0f);
    float decay = expf(-t * t);
    float g = 1.0f / (1.0f + expf(-(d * fw + fb)));
    float w = decay * g;
    if (!isfinite(w)) w = 0.0f;
    return w;
}

__device__ __forceinline__ unsigned int bf16_rne(float f) {
    unsigned int b = __float_as_uint(f);
    return (b + 0x7FFFu + ((b >> 16) & 1u)) >> 16;
}

__device__ __forceinline__ void accum8(float acc[8], uint4 u, float w) {
    acc[0] = fmaf(w, __uint_as_float(u.x << 16), acc[0]);
    acc[1] = fmaf(w, __uint_as_float(u.x & 0xFFFF0000u), acc[1]);
    acc[2] = fmaf(w, __uint_as_float(u.y << 16), acc[2]);
    acc[3] = fmaf(w, __uint_as_float(u.y & 0xFFFF0000u), acc[3]);
    acc[4] = fmaf(w, __uint_as_float(u.z << 16), acc[4]);
    acc[5] = fmaf(w, __uint_as_float(u.z & 0xFFFF0000u), acc[5]);
    acc[6] = fmaf(w, __uint_as_float(u.w << 16), acc[6]);
    acc[7] = fmaf(w, __uint_as_float(u.w & 0xFFFF0000u), acc[7]);
}

// ======================= ONE cooperative mega-kernel =========================
// P0 convert x->bf16  | P1 per-chunk bucket count | P2 colscan | P3 scan
// P4 scatter (deterministic bases, LDS atomics)   | P5 sort+aggregate
// grid.sync() between dependent phases; all work loops are grid-stride.
__global__ __launch_bounds__(MTHREADS) void mega_kernel(
    const float4* __restrict__ x4, uint2* __restrict__ xbf, int n4,
    const int* __restrict__ sender, const int* __restrict__ recv,
    const float* __restrict__ edge_len,
    const float* __restrict__ log_scale, const float* __restrict__ filter_w,
    const float* __restrict__ filter_b,
    int* __restrict__ sub, int* __restrict__ tot, int* __restrict__ boff,
    unsigned long long* __restrict__ buf,
    uint4* __restrict__ agg_bf4, int* __restrict__ deg,
    int N, int E, int nbuck, int nchunk) {
    cg::grid_group grid = cg::this_grid();
    const int tid = threadIdx.x;
    const int gsize = gridDim.x * MTHREADS;
    const int gtid = blockIdx.x * MTHREADS + tid;

    __shared__ union {
        int cnt[NBUCK_MAX];        // P1
        int cur[NBUCK_MAX];        // P4
        int scan[MTHREADS];        // P3
        struct {                   // P5 (16.9 KB)
            unsigned long long recS[CAP2];
            int cnt64[BNODES];
            int seg[BNODES + 1];
        } s;
    } U;

    // ---- P0: convert (no deps) --------------------------------------------
    for (int i = gtid; i < n4; i += gsize) {
        float4 v = x4[i];
        uint2 o;
        o.x = (bf16_rne(v.y) << 16) | bf16_rne(v.x);
        o.y = (bf16_rne(v.w) << 16) | bf16_rne(v.z);
        xbf[i] = o;
    }

    // ---- P1: per-chunk LDS histogram -> sub rows --------------------------
    for (int c = blockIdx.x; c < nchunk; c += gridDim.x) {
        for (int i = tid; i < nbuck; i += MTHREADS) U.cnt[i] = 0;
        __syncthreads();
        int base = c * EPB;
        int end = min(base + EPB, E);
        for (int e = base + tid; e < end; e += MTHREADS)
            atomicAdd(&U.cnt[recv[e] >> BSHIFT], 1);
        __syncthreads();
        size_t row = (size_t)c * nbuck;
        for (int i = tid; i < nbuck; i += MTHREADS) sub[row + i] = U.cnt[i];
        __syncthreads();
    }
    grid.sync();

    // ---- P2: colscan, coalesced (one thread per bucket) -------------------
    for (int b = gtid; b < nbuck; b += gsize) {
        int carry = 0;
        int c = 0;
        for (; c + 8 <= nchunk; c += 8) {
            int v[8];
#pragma unroll
            for (int k = 0; k < 8; ++k) v[k] = sub[(size_t)(c + k) * nbuck + b];
#pragma unroll
            for (int k = 0; k < 8; ++k) {
                sub[(size_t)(c + k) * nbuck + b] = carry;
                carry += v[k];
            }
        }
        for (; c < nchunk; ++c) {
            int v = sub[(size_t)c * nbuck + b];
            sub[(size_t)c * nbuck + b] = carry;
            carry += v;
        }
        tot[b] = carry;
    }
    grid.sync();

    // ---- P3: scan bucket totals -> boff (block 0 only) --------------------
    if (blockIdx.x == 0) {
        int chunk = (nbuck + MTHREADS - 1) / MTHREADS;
        int lo = min(tid * chunk, nbuck), hi = min(lo + chunk, nbuck);
        int s = 0;
        for (int i = lo; i < hi; ++i) s += tot[i];
        U.scan[tid] = s;
        __syncthreads();
        for (int d = 1; d < MTHREADS; d <<= 1) {
            int v = (tid >= d) ? U.scan[tid - d] : 0;
            __syncthreads();
            U.scan[tid] += v;
            __syncthreads();
        }
        int run = U.scan[tid] - s;
        for (int i = lo; i < hi; ++i) {
            boff[i] = run;
            run += tot[i];
        }
        if (hi == nbuck) boff[nbuck] = run;  // same value from all such threads
    }
    grid.sync();

    // ---- P4: scatter with deterministic bases, LDS-only atomics -----------
    {
        float scale = expf(log_scale[0]) + 1e-6f;
        float fw = filter_w[0], fb = filter_b[0];
        for (int c = blockIdx.x; c < nchunk; c += gridDim.x) {
            size_t row = (size_t)c * nbuck;
            for (int i = tid; i < nbuck; i += MTHREADS)
                U.cur[i] = boff[i] + sub[row + i];
            __syncthreads();
            int base = c * EPB;
            int end = min(base + EPB, E);
            for (int e = base + tid; e < end; e += MTHREADS) {
                int r = recv[e];
                int s = sender[e];
                float w = edge_weight(edge_len[e], scale, fw, fb);
                int pos = atomicAdd(&U.cur[r >> BSHIFT], 1);
                buf[pos] = ((unsigned long long)__float_as_uint(w) << 32)
                         | (unsigned int)(s & 0xFFFF)
                         | ((unsigned int)(r & (BNODES - 1)) << 16);
            }
            __syncthreads();
        }
    }
    grid.sync();

    // ---- P5: sort + aggregate. 512 thr, 2 nodes per 16-lane group ---------
    {
        const uint4* __restrict__ xf = (const uint4*)xbf;   // bf16 rows as uint4
        const int lane = tid & 15;
        const int grp = tid >> 4;   // 0..31
        for (int b = blockIdx.x; b < nbuck; b += gridDim.x) {
            int n0 = b << BSHIFT;
            int lo = boff[b], hi = boff[b + 1];
            float acc[2][8] = {{0.f,0.f,0.f,0.f,0.f,0.f,0.f,0.f},
                               {0.f,0.f,0.f,0.f,0.f,0.f,0.f,0.f}};
            int dcnt[2] = {0, 0};

            for (int pos = lo; pos < hi; pos += CAP2) {
                int cnt = min(CAP2, hi - pos);
                if (tid < BNODES) U.s.cnt64[tid] = 0;
                __syncthreads();

                unsigned long long rec[CAP2 / MTHREADS];
                int rnk[CAP2 / MTHREADS];
                int locl[CAP2 / MTHREADS];
#pragma unroll
                for (int k = 0; k < CAP2 / MTHREADS; ++k) {
                    int i = k * MTHREADS + tid;
                    rnk[k] = -1;
                    if (i < cnt) {
                        unsigned long long r = buf[pos + i];
                        int l = ((unsigned int)r >> 16) & (BNODES - 1);
                        rec[k] = r;
                        locl[k] = l;
                        rnk[k] = atomicAdd(&U.s.cnt64[l], 1);
                    }
                }
                __syncthreads();
                if (tid == 0) {
                    int run = 0;
#pragma unroll
                    for (int l = 0; l < BNODES; ++l) {
                        U.s.seg[l] = run;
                        run += U.s.cnt64[l];
                    }
                    U.s.seg[BNODES] = run;
                }
                __syncthreads();
#pragma unroll
                for (int k = 0; k < CAP2 / MTHREADS; ++k)
                    if (rnk[k] >= 0) U.s.recS[U.s.seg[locl[k]] + rnk[k]] = rec[k];
                __syncthreads();

#pragma unroll
                for (int which = 0; which < 2; ++which) {
                    int l = grp + which * 32;
                    int s0 = U.s.seg[l], s1 = U.s.seg[l + 1];
                    dcnt[which] += s1 - s0;
                    int i = s0;
                    for (; i + 4 <= s1; i += 4) {
                        unsigned long long r0 = U.s.recS[i];
                        unsigned long long r1 = U.s.recS[i + 1];
                        unsigned long long r2 = U.s.recS[i + 2];
                        unsigned long long r3 = U.s.recS[i + 3];
                        float w0 = __uint_as_float((unsigned int)(r0 >> 32));
                        float w1 = __uint_as_float((unsigned int)(r1 >> 32));
                        float w2 = __uint_as_float((unsigned int)(r2 >> 32));
                        float w3 = __uint_as_float((unsigned int)(r3 >> 32));
                        int s0i = (unsigned int)r0 & 0xFFFF;
                        int s1i = (unsigned int)r1 & 0xFFFF;
                        int s2i = (unsigned int)r2 & 0xFFFF;
                        int s3i = (unsigned int)r3 & 0xFFFF;
                        uint4 u0 = xf[(size_t)s0i * 16 + lane];
                        uint4 u1 = xf[(size_t)s1i * 16 + lane];
                        uint4 u2 = xf[(size_t)s2i * 16 + lane];
                        uint4 u3 = xf[(size_t)s3i * 16 + lane];
                        accum8(acc[which], u0, w0);
                        accum8(acc[which], u1, w1);
                        accum8(acc[which], u2, w2);
                        accum8(acc[which], u3, w3);
                    }
                    for (; i < s1; ++i) {
                        unsigned long long ra = U.s.recS[i];
                        float wa = __uint_as_float((unsigned int)(ra >> 32));
                        int sa = (unsigned int)ra & 0xFFFF;
                        uint4 ua = xf[(size_t)sa * 16 + lane];
                        accum8(acc[which], ua, wa);
                    }
                }
                __syncthreads();   // before next chunk overwrites recS
            }

            // writeout this bucket
#pragma unroll
            for (int which = 0; which < 2; ++which) {
                int n = n0 + grp + which * 32;
                if (n < N) {
                    uint4 o;
                    o.x = (bf16_rne(acc[which][1]) << 16) | bf16_rne(acc[which][0]);
                    o.y = (bf16_rne(acc[which][3]) << 16) | bf16_rne(acc[which][2]);
                    o.z = (bf16_rne(acc[which][5]) << 16) | bf16_rne(acc[which][4]);
                    o.w = (bf16_rne(acc[which][7]) << 16) | bf16_rne(acc[which][6]);
                    agg_bf4[(size_t)n * 16 + lane] = o;
                    if (lane == 0) deg[n] = dcnt[which];
                }
            }
        }
    }
}

// ---------------- finalize: tiled GEMM, out = x + (agg/deg) @ W --------------
__global__ __launch_bounds__(256) void finalize_kernel(
    const float* __restrict__ x, const uint4* __restrict__ agg_bf4,
    const int* __restrict__ deg, const float* __restrict__ Wm,
    float* __restrict__ out, int N) {
    __shared__ float aggS[64 * 128];  // 32 KB
    __shared__ float Ws[128 * 64];    // 32 KB
    const int n0 = blockIdx.x * 64;

    for (int i = threadIdx.x; i < 64 * 16; i += 256) {
        int r = i >> 4;
        int q = i & 15;
        int n = n0 + r;
        uint4 u = make_uint4(0u, 0u, 0u, 0u);
        if (n < N) u = agg_bf4[(size_t)n * 16 + q];
        float4 f0, f1;
        f0.x = __uint_as_float(u.x << 16);
        f0.y = __uint_as_float(u.x & 0xFFFF0000u);
        f0.z = __uint_as_float(u.y << 16);
        f0.w = __uint_as_float(u.y & 0xFFFF0000u);
        f1.x = __uint_as_float(u.z << 16);
        f1.y = __uint_as_float(u.z & 0xFFFF0000u);
        f1.z = __uint_as_float(u.w << 16);
        f1.w = __uint_as_float(u.w & 0xFFFF0000u);
        int m = (r >> 2) & 7;
        ((float4*)aggS)[r * 32 + ((2 * q) ^ m)] = f0;
        ((float4*)aggS)[r * 32 + ((2 * q + 1) ^ m)] = f1;
    }

    const int tc = threadIdx.x & 15;
    const int tr = threadIdx.x >> 4;

    float invd[4];
#pragma unroll
    for (int i = 0; i < 4; ++i) {
        int n = n0 + 4 * tr + i;
        float degf = 1.0f;
        if (n < N) degf = fmaxf((float)deg[n], 1.0f);
        invd[i] = 1.0f / degf;
    }

    for (int h = 0; h < 2; ++h) {
        for (int i = threadIdx.x; i < 128 * 16; i += 256) {
            int k = i >> 4;
            int j4 = i & 15;
            ((float4*)Ws)[k * 16 + j4] = ((const float4*)Wm)[k * 32 + h * 16 + j4];
        }
        __syncthreads();

        float acc[4][4];
#pragma unroll
        for (int i = 0; i < 4; ++i)
#pragma unroll
            for (int c = 0; c < 4; ++c) acc[i][c] = 0.f;

#pragma unroll 4
        for (int k0 = 0; k0 < 128; k0 += 4) {
            float4 ar4[4];
            const int chunk = (k0 >> 2) ^ (tr & 7);
#pragma unroll
            for (int i = 0; i < 4; ++i) {
                int r = 4 * tr + i;
                ar4[i] = ((const float4*)aggS)[r * 32 + chunk];
            }
            float4 wv4[4];
#pragma unroll
            for (int kk = 0; kk < 4; ++kk)
                wv4[kk] = *(const float4*)&Ws[(k0 + kk) * 64 + tc * 4];

            float wvv[4][4];
#pragma unroll
            for (int kk = 0; kk < 4; ++kk) {
                wvv[kk][0] = wv4[kk].x; wvv[kk][1] = wv4[kk].y;
                wvv[kk][2] = wv4[kk].z; wvv[kk][3] = wv4[kk].w;
            }
#pragma unroll
            for (int i = 0; i < 4; ++i) {
                float av[4] = {ar4[i].x, ar4[i].y, ar4[i].z, ar4[i].w};
#pragma unroll
                for (int kk = 0; kk < 4; ++kk)
#pragma unroll
                    for (int c = 0; c < 4; ++c)
                        acc[i][c] = fmaf(av[kk], wvv[kk][c], acc[i][c]);
            }
        }

#pragma unroll
        for (int i = 0; i < 4; ++i) {
            int n = n0 + 4 * tr + i;
            if (n < N) {
                size_t base = (size_t)n * FEAT + h * 64 + tc * 4;
                float4 xv = *(const float4*)&x[base];
                float4 o;
                o.x = xv.x + invd[i] * acc[i][0];
                o.y = xv.y + invd[i] * acc[i][1];
                o.z = xv.z + invd[i] * acc[i][2];
                o.w = xv.w + invd[i] * acc[i][3];
                *(float4*)&out[base] = o;
            }
        }
        __syncthreads();
    }
}

// ---------------- fallback (atomic path) ---------------
__global__ __launch_bounds__(256) void scatter_fallback(
    const float4* __restrict__ x4, const int* __restrict__ sender,
    const int* __restrict__ receiver, const float* __restrict__ edge_len,
    const float* __restrict__ log_scale, const float* __restrict__ filter_w,
    const float* __restrict__ filter_b, float* __restrict__ agg,
    float* __restrict__ deg, int E) {
    int gid = blockIdx.x * 256 + threadIdx.x;
    int e = gid >> 5;
    if (e >= E) return;
    int lane = gid & 31;
    int s = sender[e];
    int r = receiver[e];
    float scale = expf(log_scale[0]) + 1e-6f;
    float w = edge_weight(edge_len[e], scale, filter_w[0], filter_b[0]);
    float4 xv = x4[s * (FEAT / 4) + lane];
    float* dst = agg + (size_t)r * FEAT + lane * 4;
    unsafeAtomicAdd(dst + 0, w * xv.x);
    unsafeAtomicAdd(dst + 1, w * xv.y);
    unsafeAtomicAdd(dst + 2, w * xv.z);
    unsafeAtomicAdd(dst + 3, w * xv.w);
    if (lane == 0) unsafeAtomicAdd(&deg[r], 1.0f);
}

__global__ __launch_bounds__(256) void finalize_fallback(
    const float* __restrict__ x, const float* __restrict__ agg,
    const float* __restrict__ deg, const float* __restrict__ Wm,
    float* __restrict__ out, int N) {
    __shared__ float Wsf[FEAT * FEAT];
    for (int i = threadIdx.x * 4; i < FEAT * FEAT; i += 256 * 4)
        *(float4*)&Wsf[i] = *(const float4*)&Wm[i];
    __syncthreads();
    int half = threadIdx.x >> 7;
    int j = threadIdx.x & (FEAT - 1);
    for (int n0 = blockIdx.x * 2; n0 < N; n0 += gridDim.x * 2) {
        int n = n0 + half;
        if (n < N) {
            const float* arow = agg + (size_t)n * FEAT;
            float acc = 0.0f;
#pragma unroll 16
            for (int k = 0; k < FEAT; ++k) acc = fmaf(arow[k], Wsf[k * FEAT + j], acc);
            float invd = 1.0f / fmaxf(deg[n], 1.0f);
            size_t idx = (size_t)n * FEAT + j;
            out[idx] = x[idx] + invd * acc;
        }
    }
}

extern "C" void kernel_launch(void* const* d_in, const int* in_sizes, int n_in,
                              void* d_out, int out_size, void* d_ws, size_t ws_size,
                              hipStream_t stream) {
    const float* x         = (const float*)d_in[0];
    const int*   ei        = (const int*)d_in[1];
    const float* edge_len  = (const float*)d_in[2];
    const float* W_mix     = (const float*)d_in[3];
    const float* log_scale = (const float*)d_in[4];
    const float* filter_w  = (const float*)d_in[5];
    const float* filter_b  = (const float*)d_in[6];
    float* out = (float*)d_out;

    const int N = in_sizes[0] / FEAT;
    const int E = in_sizes[1] / 2;
    const int* sender   = ei;
    const int* receiver = ei + E;
    const int nbuck = (N + BNODES - 1) >> BSHIFT;
    const int nchunk = (E + EPB - 1) / EPB;

    size_t xbf_bytes  = (size_t)N * FEAT * 2;
    size_t aggb_bytes = (size_t)N * FEAT * 2;
    size_t buf_bytes  = ((size_t)E + 16) * 8;
    size_t sub_bytes  = (((size_t)nchunk * nbuck * 4) + 63) & ~(size_t)63;
    size_t tot_bytes  = (((size_t)nbuck * 4) + 63) & ~(size_t)63;
    size_t boff_bytes = (((size_t)(nbuck + 1) * 4) + 63) & ~(size_t)63;
    size_t deg_bytes  = (((size_t)N * 4) + 63) & ~(size_t)63;
    size_t fixed = xbf_bytes + aggb_bytes + buf_bytes + sub_bytes + tot_bytes +
                   boff_bytes + deg_bytes;

    // one-time: cooperative-launch capability + co-resident grid capacity
    static int s_grid = -2;
    if (s_grid == -2) {
        int dev = 0, coop = 0;
        (void)hipGetDevice(&dev);
        (void)hipDeviceGetAttribute(&coop, hipDeviceAttributeCooperativeLaunch, dev);
        if (coop) {
            hipDeviceProp_t prop;
            (void)hipGetDeviceProperties(&prop, dev);
            int nb = 0;
            (void)hipOccupancyMaxActiveBlocksPerMultiprocessor(&nb, mega_kernel,
                                                               MTHREADS, 0);
            int g = (nb >= 1) ? nb * prop.multiProcessorCount : 0;
            if (g > 1024) g = 1024;
            s_grid = g;
        } else {
            s_grid = 0;
        }
    }

    if (fixed <= ws_size && N <= 65536 && s_grid > 0) {
        char* p = (char*)d_ws;
        uint2* xbf    = (uint2*)p;                        p += xbf_bytes;
        uint4* agg_bf = (uint4*)p;                        p += aggb_bytes;
        unsigned long long* buf = (unsigned long long*)p; p += buf_bytes;
        int* sub  = (int*)p;                              p += sub_bytes;
        int* tot  = (int*)p;                              p += tot_bytes;
        int* boff = (int*)p;                              p += boff_bytes;
        int* deg  = (int*)p;

        int n4 = N * (FEAT / 4);

        const float4* x4p = (const float4*)x;
        int Nv = N, Ev = E, nbv = nbuck, ncv = nchunk, n4v = n4;
        const int* sndp = sender;
        const int* rcvp = receiver;
        void* args[] = {
            (void*)&x4p, (void*)&xbf, (void*)&n4v,
            (void*)&sndp, (void*)&rcvp, (void*)&edge_len,
            (void*)&log_scale, (void*)&filter_w, (void*)&filter_b,
            (void*)&sub, (void*)&tot, (void*)&boff,
            (void*)&buf, (void*)&agg_bf, (void*)&deg,
            (void*)&Nv, (void*)&Ev, (void*)&nbv, (void*)&ncv
        };
        hipError_t err = hipLaunchCooperativeKernel(
            (void*)mega_kernel, dim3(s_grid), dim3(MTHREADS), args, 0, stream);
        if (err == hipSuccess) {
            int fblocks = (N + 63) / 64;
            finalize_kernel<<<fblocks, 256, 0, stream>>>(
                x, (const uint4*)agg_bf, deg, W_mix, out, N);
            return;
        }
        s_grid = 0;   // cooperative launch unusable: permanent fallback
    }

    // atomic fallback path
    {
        float* agg = (float*)d_ws;
        float* degf = agg + (size_t)N * FEAT;
        (void)hipMemsetAsync(agg, 0, ((size_t)N * FEAT + N) * sizeof(float), stream);
        int sblocks = (E * 32 + 255) / 256;
        scatter_fallback<<<sblocks, 256, 0, stream>>>(
            (const float4*)x, sender, receiver, edge_len,
            log_scale, filter_w, filter_b, agg, degf, E);
        finalize_fallback<<<512, 256, 0, stream>>>(x, agg, degf, W_mix, out, N);
    }
}

// Round 6
// 304.400 us; speedup vs baseline: 1.2923x; 1.2923x over previous
//
#include <hip/hip_runtime.h>
#include <math.h>

#define FEAT 128
#define BSHIFT 4            // 16 nodes per bucket
#define BNODES 16
#define CAP_REC 1024        // records per LDS sort chunk (8 KB)
#define NBUCK_MAX 4096      // N <= 65536
#define EPB 16384           // edges per scatter chunk (long reserved runs)

__device__ __forceinline__ float edge_weight(float d, float scale, float fw, float fb) {
    // scale already includes +1e-6
    float t = fmaxf(d / scale, 0.0f);
    float decay = expf(-t * t);
    float g = 1.0f / (1.0f + expf(-(d * fw + fb)));
    float w = decay * g;
    if (!isfinite(w)) w = 0.0f;
    return w;
}

__device__ __forceinline__ unsigned int bf16_rne(float f) {
    unsigned int b = __float_as_uint(f);
    return (b + 0x7FFFu + ((b >> 16) & 1u)) >> 16;
}

__device__ __forceinline__ void accum8(float acc[8], uint4 u, float w) {
    acc[0] = fmaf(w, __uint_as_float(u.x << 16), acc[0]);
    acc[1] = fmaf(w, __uint_as_float(u.x & 0xFFFF0000u), acc[1]);
    acc[2] = fmaf(w, __uint_as_float(u.y << 16), acc[2]);
    acc[3] = fmaf(w, __uint_as_float(u.y & 0xFFFF0000u), acc[3]);
    acc[4] = fmaf(w, __uint_as_float(u.z << 16), acc[4]);
    acc[5] = fmaf(w, __uint_as_float(u.z & 0xFFFF0000u), acc[5]);
    acc[6] = fmaf(w, __uint_as_float(u.w << 16), acc[6]);
    acc[7] = fmaf(w, __uint_as_float(u.w & 0xFFFF0000u), acc[7]);
}

// ==== K1: blocks [0,nchunk): two-pass reserve-scatter; rest: x->bf16 convert.
// Pass 1: LDS histogram of this chunk. Reserve: one global atomicAdd per
// nonzero bucket -> contiguous run inside the bucket's fixed-cap region.
// Pass 2: LDS-atomic rank, write records. No global prefix sums needed.
__global__ __launch_bounds__(256) void convert_scatter_kernel(
    const float4* __restrict__ x4, uint2* __restrict__ xbf, int n4,
    const int* __restrict__ sender, const int* __restrict__ recv,
    const float* __restrict__ edge_len,
    const float* __restrict__ log_scale, const float* __restrict__ filter_w,
    const float* __restrict__ filter_b,
    int* __restrict__ gcnt, unsigned long long* __restrict__ buf,
    int E, int nbuck, int cap, int nchunk) {
    __shared__ int cnt[NBUCK_MAX];   // 16 KB max
    const int tid = threadIdx.x;

    if ((int)blockIdx.x >= nchunk) {            // ---- convert part ----
        int i = ((int)blockIdx.x - nchunk) * 256 + tid;
        if (i >= n4) return;
        float4 v = x4[i];
        uint2 o;
        o.x = (bf16_rne(v.y) << 16) | bf16_rne(v.x);
        o.y = (bf16_rne(v.w) << 16) | bf16_rne(v.z);
        xbf[i] = o;
        return;
    }

    // ---- scatter part ----
    const int c = blockIdx.x;
    for (int i = tid; i < nbuck; i += 256) cnt[i] = 0;
    __syncthreads();
    const int base = c * EPB;
    const int end = min(base + EPB, E);
    for (int e = base + tid; e < end; e += 256)
        atomicAdd(&cnt[recv[e] >> BSHIFT], 1);
    __syncthreads();
    for (int i = tid; i < nbuck; i += 256) {
        int cc = cnt[i];
        int b0 = cc ? atomicAdd(&gcnt[i], cc) : 0;
        cnt[i] = i * cap + b0;      // repurpose as cur[]
    }
    __syncthreads();
    float scale = expf(log_scale[0]) + 1e-6f;
    float fw = filter_w[0], fb = filter_b[0];
    for (int e = base + tid; e < end; e += 256) {
        int r = recv[e];
        int s = sender[e];
        float w = edge_weight(edge_len[e], scale, fw, fb);
        int bk = r >> BSHIFT;
        int pos = atomicAdd(&cnt[bk], 1);
        if (pos < (bk + 1) * cap)   // overflow guard (never hit for cap=2*mean)
            buf[pos] = ((unsigned long long)__float_as_uint(w) << 32)
                     | (unsigned int)(s & 0xFFFF)
                     | ((unsigned int)(r & (BNODES - 1)) << 16);
    }
}

// ==== K2: sort + aggregate + FUSED per-node GEMM epilogue ====================
// Gather phase identical to the proven R1 kernel (46.5 us). Then acc rows are
// staged into the same LDS (union, stride 130 to avoid bank conflicts) and
// each thread computes 8 outputs of its node: out = x + (acc @ W) * invd.
// This deletes the agg_bf round-trip and the separate finalize dispatch.
__global__ __launch_bounds__(256) void aggregate_gemm_kernel(
    const uint4* __restrict__ xbf4, const unsigned long long* __restrict__ buf,
    const int* __restrict__ gcnt, const float* __restrict__ x,
    const float* __restrict__ Wm, float* __restrict__ out, int N, int cap) {
    __shared__ union {
        unsigned long long recS[CAP_REC];   // 8 KB
        float accS[BNODES * 130];           // 8.32 KB, padded stride
    } S;
    __shared__ int cnt16[BNODES];
    __shared__ int segoff[BNODES + 1];

    const int b = blockIdx.x;
    const int n0 = b << BSHIFT;
    const int tid = threadIdx.x;
    const int lane = tid & 15;
    const int grp = tid >> 4;     // 0..15: one node per 16-lane group

    const int lo = b * cap;
    const int hi = lo + min(gcnt[b], cap);

    float acc[8] = {0.f,0.f,0.f,0.f,0.f,0.f,0.f,0.f};
    int dcnt = 0;

    for (int pos = lo; pos < hi; pos += CAP_REC) {
        int cnt = min(CAP_REC, hi - pos);
        if (tid < BNODES) cnt16[tid] = 0;
        __syncthreads();

        unsigned long long rec[CAP_REC / 256];
        int rnk[CAP_REC / 256];
        int locl[CAP_REC / 256];
#pragma unroll
        for (int k = 0; k < CAP_REC / 256; ++k) {
            int i = k * 256 + tid;
            rnk[k] = -1;
            if (i < cnt) {
                unsigned long long r = buf[pos + i];
                int l = ((unsigned int)r >> 16) & (BNODES - 1);
                rec[k] = r;
                locl[k] = l;
                rnk[k] = atomicAdd(&cnt16[l], 1);
            }
        }
        __syncthreads();
        if (tid == 0) {
            int run = 0;
#pragma unroll
            for (int l = 0; l < BNODES; ++l) { segoff[l] = run; run += cnt16[l]; }
            segoff[BNODES] = run;
        }
        __syncthreads();
#pragma unroll
        for (int k = 0; k < CAP_REC / 256; ++k)
            if (rnk[k] >= 0) S.recS[segoff[locl[k]] + rnk[k]] = rec[k];
        __syncthreads();

        // accumulate: group grp handles local node grp; 4-deep unroll
        {
            int s0 = segoff[grp], s1 = segoff[grp + 1];
            dcnt += s1 - s0;
            int i = s0;
            for (; i + 4 <= s1; i += 4) {
                unsigned long long r0 = S.recS[i];
                unsigned long long r1 = S.recS[i + 1];
                unsigned long long r2 = S.recS[i + 2];
                unsigned long long r3 = S.recS[i + 3];
                float w0 = __uint_as_float((unsigned int)(r0 >> 32));
                float w1 = __uint_as_float((unsigned int)(r1 >> 32));
                float w2 = __uint_as_float((unsigned int)(r2 >> 32));
                float w3 = __uint_as_float((unsigned int)(r3 >> 32));
                int s0i = (unsigned int)r0 & 0xFFFF;
                int s1i = (unsigned int)r1 & 0xFFFF;
                int s2i = (unsigned int)r2 & 0xFFFF;
                int s3i = (unsigned int)r3 & 0xFFFF;
                uint4 u0 = xbf4[(size_t)s0i * 16 + lane];
                uint4 u1 = xbf4[(size_t)s1i * 16 + lane];
                uint4 u2 = xbf4[(size_t)s2i * 16 + lane];
                uint4 u3 = xbf4[(size_t)s3i * 16 + lane];
                accum8(acc, u0, w0);
                accum8(acc, u1, w1);
                accum8(acc, u2, w2);
                accum8(acc, u3, w3);
            }
            for (; i < s1; ++i) {
                unsigned long long ra = S.recS[i];
                float wa = __uint_as_float((unsigned int)(ra >> 32));
                int sa = (unsigned int)ra & 0xFFFF;
                uint4 ua = xbf4[(size_t)sa * 16 + lane];
                accum8(acc, ua, wa);
            }
        }
        __syncthreads();   // before next chunk overwrites recS
    }

    // ---- fused GEMM epilogue -------------------------------------------
    // stage acc rows: accS[node][k], stride 130 words (bank-conflict-free)
#pragma unroll
    for (int k = 0; k < 8; ++k) S.accS[grp * 130 + lane * 8 + k] = acc[k];
    __syncthreads();

    const float4* W4 = (const float4*)Wm;   // W[k][j], row-major 128x128 f32
    float o[8] = {0.f,0.f,0.f,0.f,0.f,0.f,0.f,0.f};
    for (int k0 = 0; k0 < FEAT; k0 += 8) {
        float a[8];
#pragma unroll
        for (int kk = 0; kk < 8; ++kk) a[kk] = S.accS[grp * 130 + k0 + kk];
#pragma unroll
        for (int kk = 0; kk < 8; ++kk) {
            float4 w0 = W4[(k0 + kk) * 32 + lane * 2];
            float4 w1 = W4[(k0 + kk) * 32 + lane * 2 + 1];
            o[0] = fmaf(a[kk], w0.x, o[0]);
            o[1] = fmaf(a[kk], w0.y, o[1]);
            o[2] = fmaf(a[kk], w0.z, o[2]);
            o[3] = fmaf(a[kk], w0.w, o[3]);
            o[4] = fmaf(a[kk], w1.x, o[4]);
            o[5] = fmaf(a[kk], w1.y, o[5]);
            o[6] = fmaf(a[kk], w1.z, o[6]);
            o[7] = fmaf(a[kk], w1.w, o[7]);
        }
    }

    int n = n0 + grp;
    if (n < N) {
        float invd = 1.0f / fmaxf((float)dcnt, 1.0f);
        size_t basei = (size_t)n * FEAT + lane * 8;
        float4 xv0 = *(const float4*)&x[basei];
        float4 xv1 = *(const float4*)&x[basei + 4];
        float4 r0, r1;
        r0.x = xv0.x + invd * o[0];
        r0.y = xv0.y + invd * o[1];
        r0.z = xv0.z + invd * o[2];
        r0.w = xv0.w + invd * o[3];
        r1.x = xv1.x + invd * o[4];
        r1.y = xv1.y + invd * o[5];
        r1.z = xv1.z + invd * o[6];
        r1.w = xv1.w + invd * o[7];
        *(float4*)&out[basei] = r0;
        *(float4*)&out[basei + 4] = r1;
    }
}

// ---------------- fallback (atomic path) ---------------
__global__ __launch_bounds__(256) void scatter_fallback(
    const float4* __restrict__ x4, const int* __restrict__ sender,
    const int* __restrict__ receiver, const float* __restrict__ edge_len,
    const float* __restrict__ log_scale, const float* __restrict__ filter_w,
    const float* __restrict__ filter_b, float* __restrict__ agg,
    float* __restrict__ deg, int E) {
    int gid = blockIdx.x * 256 + threadIdx.x;
    int e = gid >> 5;
    if (e >= E) return;
    int lane = gid & 31;
    int s = sender[e];
    int r = receiver[e];
    float scale = expf(log_scale[0]) + 1e-6f;
    float w = edge_weight(edge_len[e], scale, filter_w[0], filter_b[0]);
    float4 xv = x4[s * (FEAT / 4) + lane];
    float* dst = agg + (size_t)r * FEAT + lane * 4;
    unsafeAtomicAdd(dst + 0, w * xv.x);
    unsafeAtomicAdd(dst + 1, w * xv.y);
    unsafeAtomicAdd(dst + 2, w * xv.z);
    unsafeAtomicAdd(dst + 3, w * xv.w);
    if (lane == 0) unsafeAtomicAdd(&deg[r], 1.0f);
}

__global__ __launch_bounds__(256) void finalize_fallback(
    const float* __restrict__ x, const float* __restrict__ agg,
    const float* __restrict__ deg, const float* __restrict__ Wm,
    float* __restrict__ out, int N) {
    __shared__ float Wsf[FEAT * FEAT];
    for (int i = threadIdx.x * 4; i < FEAT * FEAT; i += 256 * 4)
        *(float4*)&Wsf[i] = *(const float4*)&Wm[i];
    __syncthreads();
    int half = threadIdx.x >> 7;
    int j = threadIdx.x & (FEAT - 1);
    for (int n0 = blockIdx.x * 2; n0 < N; n0 += gridDim.x * 2) {
        int n = n0 + half;
        if (n < N) {
            const float* arow = agg + (size_t)n * FEAT;
            float acc = 0.0f;
#pragma unroll 16
            for (int k = 0; k < FEAT; ++k) acc = fmaf(arow[k], Wsf[k * FEAT + j], acc);
            float invd = 1.0f / fmaxf(deg[n], 1.0f);
            size_t idx = (size_t)n * FEAT + j;
            out[idx] = x[idx] + invd * acc;
        }
    }
}

extern "C" void kernel_launch(void* const* d_in, const int* in_sizes, int n_in,
                              void* d_out, int out_size, void* d_ws, size_t ws_size,
                              hipStream_t stream) {
    const float* x         = (const float*)d_in[0];
    const int*   ei        = (const int*)d_in[1];
    const float* edge_len  = (const float*)d_in[2];
    const float* W_mix     = (const float*)d_in[3];
    const float* log_scale = (const float*)d_in[4];
    const float* filter_w  = (const float*)d_in[5];
    const float* filter_b  = (const float*)d_in[6];
    float* out = (float*)d_out;

    const int N = in_sizes[0] / FEAT;
    const int E = in_sizes[1] / 2;
    const int* sender   = ei;
    const int* receiver = ei + E;
    const int nbuck = (N + BNODES - 1) >> BSHIFT;
    const int nchunk = (E + EPB - 1) / EPB;

    size_t xbf_bytes  = (size_t)N * FEAT * 2;
    size_t gcnt_bytes = (((size_t)nbuck * 4) + 63) & ~(size_t)63;

    // bucket capacity: 2x mean + slack, shrunk to fit workspace
    int mean = E / nbuck + 1;
    int cap = ((2 * mean + 256) + 63) & ~63;
    if (cap > 8192) cap = 8192;
    size_t avail = (ws_size > xbf_bytes + gcnt_bytes)
                 ? ws_size - xbf_bytes - gcnt_bytes : 0;
    size_t need = (size_t)nbuck * cap * 8;
    if (need > avail) {
        cap = (int)((avail / ((size_t)nbuck * 8)) & ~(size_t)63);
        need = (size_t)nbuck * cap * 8;
    }
    bool ok = (N <= 65536) && (nbuck <= NBUCK_MAX) &&
              (cap >= mean + mean / 2 + 64) && (need <= avail);

    if (ok) {
        char* p = (char*)d_ws;
        uint2* xbf = (uint2*)p;                           p += xbf_bytes;
        int* gcnt  = (int*)p;                             p += gcnt_bytes;
        unsigned long long* buf = (unsigned long long*)p;

        (void)hipMemsetAsync(gcnt, 0, (size_t)nbuck * sizeof(int), stream);

        int n4 = N * (FEAT / 4);
        int cblocks = (n4 + 255) / 256;
        convert_scatter_kernel<<<nchunk + cblocks, 256, 0, stream>>>(
            (const float4*)x, xbf, n4, sender, receiver, edge_len,
            log_scale, filter_w, filter_b, gcnt, buf, E, nbuck, cap, nchunk);
        aggregate_gemm_kernel<<<nbuck, 256, 0, stream>>>(
            (const uint4*)xbf, buf, gcnt, x, W_mix, out, N, cap);
    } else {
        float* agg = (float*)d_ws;
        float* degf = agg + (size_t)N * FEAT;
        (void)hipMemsetAsync(agg, 0, ((size_t)N * FEAT + N) * sizeof(float), stream);
        int sblocks = (E * 32 + 255) / 256;
        scatter_fallback<<<sblocks, 256, 0, stream>>>(
            (const float4*)x, sender, receiver, edge_len,
            log_scale, filter_w, filter_b, agg, degf, E);
        finalize_fallback<<<512, 256, 0, stream>>>(x, agg, degf, W_mix, out, N);
    }
}

// Round 7
// 227.288 us; speedup vs baseline: 1.7308x; 1.3393x over previous
//
#include <hip/hip_runtime.h>
#include <math.h>

#define FEAT 128
#define BSHIFT 6            // 64 nodes per COARSE bucket (long scatter runs)
#define BNODES 64
#define FB 16               // fine slice: 16 nodes, one block each
#define CAP_REC 1024        // records per LDS sort chunk (8 KB)
#define NBUCK_MAX 1024      // N <= 65536 -> nbuck <= 1024
#define EPB 4096            // edges per scatter chunk: 367 blocks at E=1.5M

__device__ __forceinline__ float edge_weight(float d, float scale, float fw, float fb) {
    // scale already includes +1e-6
    float t = fmaxf(d / scale, 0.0f);
    float decay = expf(-t * t);
    float g = 1.0f / (1.0f + expf(-(d * fw + fb)));
    float w = decay * g;
    if (!isfinite(w)) w = 0.0f;
    return w;
}

__device__ __forceinline__ unsigned int bf16_rne(float f) {
    unsigned int b = __float_as_uint(f);
    return (b + 0x7FFFu + ((b >> 16) & 1u)) >> 16;
}

__device__ __forceinline__ void accum8(float acc[8], uint4 u, float w) {
    acc[0] = fmaf(w, __uint_as_float(u.x << 16), acc[0]);
    acc[1] = fmaf(w, __uint_as_float(u.x & 0xFFFF0000u), acc[1]);
    acc[2] = fmaf(w, __uint_as_float(u.y << 16), acc[2]);
    acc[3] = fmaf(w, __uint_as_float(u.y & 0xFFFF0000u), acc[3]);
    acc[4] = fmaf(w, __uint_as_float(u.z << 16), acc[4]);
    acc[5] = fmaf(w, __uint_as_float(u.z & 0xFFFF0000u), acc[5]);
    acc[6] = fmaf(w, __uint_as_float(u.w << 16), acc[6]);
    acc[7] = fmaf(w, __uint_as_float(u.w & 0xFFFF0000u), acc[7]);
}

// ==== K1: blocks [0,nchunk): two-pass reserve-scatter; rest: x->bf16 convert.
// Scatter blocks FIRST so the long pole starts immediately; convert blocks
// co-schedule into remaining CU capacity. Reservation: per-chunk LDS
// histogram, ONE global atomicAdd per nonzero bucket reserves a contiguous
// run in that bucket's fixed-cap region -> no count/colscan/scan kernels.
__global__ __launch_bounds__(256) void convert_scatter_kernel(
    const float4* __restrict__ x4, uint2* __restrict__ xbf, int n4,
    const int* __restrict__ sender, const int* __restrict__ recv,
    const float* __restrict__ edge_len,
    const float* __restrict__ log_scale, const float* __restrict__ filter_w,
    const float* __restrict__ filter_b,
    int* __restrict__ gcnt, unsigned long long* __restrict__ buf,
    int E, int nbuck, int cap, int nchunk) {
    __shared__ int cnt[NBUCK_MAX];   // 4 KB
    const int tid = threadIdx.x;

    if ((int)blockIdx.x >= nchunk) {            // ---- convert part ----
        int i = ((int)blockIdx.x - nchunk) * 256 + tid;
        if (i >= n4) return;
        float4 v = x4[i];
        uint2 o;
        o.x = (bf16_rne(v.y) << 16) | bf16_rne(v.x);
        o.y = (bf16_rne(v.w) << 16) | bf16_rne(v.z);
        xbf[i] = o;
        return;
    }

    // ---- scatter part ----
    const int c = blockIdx.x;
    for (int i = tid; i < nbuck; i += 256) cnt[i] = 0;
    __syncthreads();
    const int base = c * EPB;
    const int end = min(base + EPB, E);
    for (int e = base + tid; e < end; e += 256)
        atomicAdd(&cnt[recv[e] >> BSHIFT], 1);
    __syncthreads();
    for (int i = tid; i < nbuck; i += 256) {
        int cc = cnt[i];
        int b0 = cc ? atomicAdd(&gcnt[i], cc) : 0;
        cnt[i] = i * cap + b0;      // repurpose as run cursor
    }
    __syncthreads();
    float scale = expf(log_scale[0]) + 1e-6f;
    float fw = filter_w[0], fb = filter_b[0];
    for (int e = base + tid; e < end; e += 256) {
        int r = recv[e];
        int s = sender[e];
        float w = edge_weight(edge_len[e], scale, fw, fb);
        int bk = r >> BSHIFT;
        int pos = atomicAdd(&cnt[bk], 1);
        if (pos < (bk + 1) * cap)   // safety only; cap >= mean+5sigma
            buf[pos] = ((unsigned long long)__float_as_uint(w) << 32)
                     | (unsigned int)(s & 0xFFFF)
                     | ((unsigned int)(r & (BNODES - 1)) << 16);
    }
}

// ==== K2: sort+aggregate (R3-proven form). 4 blocks per coarse bucket; each
// filters its 16-node slice, LDS counting-sorts, register-accumulates. ------
__global__ __launch_bounds__(256) void bucket_sort_aggregate_kernel(
    const uint4* __restrict__ xbf4, const unsigned long long* __restrict__ buf,
    const int* __restrict__ gcnt, uint4* __restrict__ agg_bf4,
    int* __restrict__ deg, int N, int cap) {
    __shared__ unsigned long long recS[CAP_REC];   // 8 KB
    __shared__ int cnt16[FB];
    __shared__ int segoff[FB + 1];

    int cb = blockIdx.x >> 2;          // coarse bucket
    int q  = blockIdx.x & 3;           // which 16-node slice
    int n0 = (cb << BSHIFT) + (q << 4);
    int nEnd = min(n0 + FB, N);
    int lo = cb * cap;
    int hi = lo + min(gcnt[cb], cap);
    int tid = threadIdx.x;
    int lane = tid & 15;
    int grp = tid >> 4;                // 0..15: one fine-local node per group

    float acc[8] = {0.f,0.f,0.f,0.f,0.f,0.f,0.f,0.f};
    int dcnt = 0;

    for (int pos = lo; pos < hi; pos += CAP_REC) {
        int cnt = min(CAP_REC, hi - pos);
        if (tid < FB) cnt16[tid] = 0;
        __syncthreads();

        unsigned long long rec[CAP_REC / 256];
        int lr[CAP_REC / 256];         // -1 = not kept, else (rank<<4)|l4
#pragma unroll
        for (int k = 0; k < CAP_REC / 256; ++k) {
            int i = k * 256 + tid;
            lr[k] = -1;
            if (i < cnt) {
                unsigned long long r = buf[pos + i];
                int l6 = ((unsigned int)r >> 16) & 63;
                if ((l6 >> 4) == q) {
                    int l = l6 & 15;
                    int rk = atomicAdd(&cnt16[l], 1);
                    lr[k] = (rk << 4) | l;
                    rec[k] = r;
                }
            }
        }
        __syncthreads();
        if (tid == 0) {
            int run = 0;
#pragma unroll
            for (int l = 0; l < FB; ++l) { segoff[l] = run; run += cnt16[l]; }
            segoff[FB] = run;
        }
        __syncthreads();
#pragma unroll
        for (int k = 0; k < CAP_REC / 256; ++k)
            if (lr[k] >= 0) recS[segoff[lr[k] & 15] + (lr[k] >> 4)] = rec[k];
        __syncthreads();

        // accumulate: group grp handles fine-local node grp; 4-deep unroll
        {
            int s0 = segoff[grp], s1 = segoff[grp + 1];
            dcnt += s1 - s0;
            int i = s0;
            for (; i + 4 <= s1; i += 4) {
                unsigned long long r0 = recS[i];
                unsigned long long r1 = recS[i + 1];
                unsigned long long r2 = recS[i + 2];
                unsigned long long r3 = recS[i + 3];
                float w0 = __uint_as_float((unsigned int)(r0 >> 32));
                float w1 = __uint_as_float((unsigned int)(r1 >> 32));
                float w2 = __uint_as_float((unsigned int)(r2 >> 32));
                float w3 = __uint_as_float((unsigned int)(r3 >> 32));
                int s0i = (unsigned int)r0 & 0xFFFF;
                int s1i = (unsigned int)r1 & 0xFFFF;
                int s2i = (unsigned int)r2 & 0xFFFF;
                int s3i = (unsigned int)r3 & 0xFFFF;
                uint4 u0 = xbf4[(size_t)s0i * 16 + lane];
                uint4 u1 = xbf4[(size_t)s1i * 16 + lane];
                uint4 u2 = xbf4[(size_t)s2i * 16 + lane];
                uint4 u3 = xbf4[(size_t)s3i * 16 + lane];
                accum8(acc, u0, w0);
                accum8(acc, u1, w1);
                accum8(acc, u2, w2);
                accum8(acc, u3, w3);
            }
            for (; i < s1; ++i) {
                unsigned long long ra = recS[i];
                float wa = __uint_as_float((unsigned int)(ra >> 32));
                int sa = (unsigned int)ra & 0xFFFF;
                uint4 ua = xbf4[(size_t)sa * 16 + lane];
                accum8(acc, ua, wa);
            }
        }
        __syncthreads();   // before next chunk overwrites recS
    }

    // writeout: bf16-pack; lane owns features lane*8..lane*8+7
    {
        int n = n0 + grp;
        if (n < nEnd) {
            uint4 o;
            o.x = (bf16_rne(acc[1]) << 16) | bf16_rne(acc[0]);
            o.y = (bf16_rne(acc[3]) << 16) | bf16_rne(acc[2]);
            o.z = (bf16_rne(acc[5]) << 16) | bf16_rne(acc[4]);
            o.w = (bf16_rne(acc[7]) << 16) | bf16_rne(acc[6]);
            agg_bf4[(size_t)n * 16 + lane] = o;
            if (lane == 0) deg[n] = dcnt;
        }
    }
}

// ---------------- finalize: tiled GEMM, out = x + (agg/deg) @ W --------------
__global__ __launch_bounds__(256) void finalize_kernel(
    const float* __restrict__ x, const uint4* __restrict__ agg_bf4,
    const int* __restrict__ deg, const float* __restrict__ Wm,
    float* __restrict__ out, int N) {
    __shared__ float aggS[64 * 128];  // 32 KB
    __shared__ float Ws[128 * 64];    // 32 KB
    const int n0 = blockIdx.x * 64;

    for (int i = threadIdx.x; i < 64 * 16; i += 256) {
        int r = i >> 4;
        int q = i & 15;
        int n = n0 + r;
        uint4 u = make_uint4(0u, 0u, 0u, 0u);
        if (n < N) u = agg_bf4[(size_t)n * 16 + q];
        float4 f0, f1;
        f0.x = __uint_as_float(u.x << 16);
        f0.y = __uint_as_float(u.x & 0xFFFF0000u);
        f0.z = __uint_as_float(u.y << 16);
        f0.w = __uint_as_float(u.y & 0xFFFF0000u);
        f1.x = __uint_as_float(u.z << 16);
        f1.y = __uint_as_float(u.z & 0xFFFF0000u);
        f1.z = __uint_as_float(u.w << 16);
        f1.w = __uint_as_float(u.w & 0xFFFF0000u);
        int m = (r >> 2) & 7;
        ((float4*)aggS)[r * 32 + ((2 * q) ^ m)] = f0;
        ((float4*)aggS)[r * 32 + ((2 * q + 1) ^ m)] = f1;
    }

    const int tc = threadIdx.x & 15;
    const int tr = threadIdx.x >> 4;

    float invd[4];
#pragma unroll
    for (int i = 0; i < 4; ++i) {
        int n = n0 + 4 * tr + i;
        float degf = 1.0f;
        if (n < N) degf = fmaxf((float)deg[n], 1.0f);
        invd[i] = 1.0f / degf;
    }

    for (int h = 0; h < 2; ++h) {
        for (int i = threadIdx.x; i < 128 * 16; i += 256) {
            int k = i >> 4;
            int j4 = i & 15;
            ((float4*)Ws)[k * 16 + j4] = ((const float4*)Wm)[k * 32 + h * 16 + j4];
        }
        __syncthreads();

        float acc[4][4];
#pragma unroll
        for (int i = 0; i < 4; ++i)
#pragma unroll
            for (int c = 0; c < 4; ++c) acc[i][c] = 0.f;

#pragma unroll 4
        for (int k0 = 0; k0 < 128; k0 += 4) {
            float4 ar4[4];
            const int chunk = (k0 >> 2) ^ (tr & 7);
#pragma unroll
            for (int i = 0; i < 4; ++i) {
                int r = 4 * tr + i;
                ar4[i] = ((const float4*)aggS)[r * 32 + chunk];
            }
            float4 wv4[4];
#pragma unroll
            for (int kk = 0; kk < 4; ++kk)
                wv4[kk] = *(const float4*)&Ws[(k0 + kk) * 64 + tc * 4];

            float wvv[4][4];
#pragma unroll
            for (int kk = 0; kk < 4; ++kk) {
                wvv[kk][0] = wv4[kk].x; wvv[kk][1] = wv4[kk].y;
                wvv[kk][2] = wv4[kk].z; wvv[kk][3] = wv4[kk].w;
            }
#pragma unroll
            for (int i = 0; i < 4; ++i) {
                float av[4] = {ar4[i].x, ar4[i].y, ar4[i].z, ar4[i].w};
#pragma unroll
                for (int kk = 0; kk < 4; ++kk)
#pragma unroll
                    for (int c = 0; c < 4; ++c)
                        acc[i][c] = fmaf(av[kk], wvv[kk][c], acc[i][c]);
            }
        }

#pragma unroll
        for (int i = 0; i < 4; ++i) {
            int n = n0 + 4 * tr + i;
            if (n < N) {
                size_t base = (size_t)n * FEAT + h * 64 + tc * 4;
                float4 xv = *(const float4*)&x[base];
                float4 o;
                o.x = xv.x + invd[i] * acc[i][0];
                o.y = xv.y + invd[i] * acc[i][1];
                o.z = xv.z + invd[i] * acc[i][2];
                o.w = xv.w + invd[i] * acc[i][3];
                *(float4*)&out[base] = o;
            }
        }
        __syncthreads();
    }
}

// ---------------- fallback (atomic path) ---------------
__global__ __launch_bounds__(256) void scatter_fallback(
    const float4* __restrict__ x4, const int* __restrict__ sender,
    const int* __restrict__ receiver, const float* __restrict__ edge_len,
    const float* __restrict__ log_scale, const float* __restrict__ filter_w,
    const float* __restrict__ filter_b, float* __restrict__ agg,
    float* __restrict__ deg, int E) {
    int gid = blockIdx.x * 256 + threadIdx.x;
    int e = gid >> 5;
    if (e >= E) return;
    int lane = gid & 31;
    int s = sender[e];
    int r = receiver[e];
    float scale = expf(log_scale[0]) + 1e-6f;
    float w = edge_weight(edge_len[e], scale, filter_w[0], filter_b[0]);
    float4 xv = x4[s * (FEAT / 4) + lane];
    float* dst = agg + (size_t)r * FEAT + lane * 4;
    unsafeAtomicAdd(dst + 0, w * xv.x);
    unsafeAtomicAdd(dst + 1, w * xv.y);
    unsafeAtomicAdd(dst + 2, w * xv.z);
    unsafeAtomicAdd(dst + 3, w * xv.w);
    if (lane == 0) unsafeAtomicAdd(&deg[r], 1.0f);
}

__global__ __launch_bounds__(256) void finalize_fallback(
    const float* __restrict__ x, const float* __restrict__ agg,
    const float* __restrict__ deg, const float* __restrict__ Wm,
    float* __restrict__ out, int N) {
    __shared__ float Wsf[FEAT * FEAT];
    for (int i = threadIdx.x * 4; i < FEAT * FEAT; i += 256 * 4)
        *(float4*)&Wsf[i] = *(const float4*)&Wm[i];
    __syncthreads();
    int half = threadIdx.x >> 7;
    int j = threadIdx.x & (FEAT - 1);
    for (int n0 = blockIdx.x * 2; n0 < N; n0 += gridDim.x * 2) {
        int n = n0 + half;
        if (n < N) {
            const float* arow = agg + (size_t)n * FEAT;
            float acc = 0.0f;
#pragma unroll 16
            for (int k = 0; k < FEAT; ++k) acc = fmaf(arow[k], Wsf[k * FEAT + j], acc);
            float invd = 1.0f / fmaxf(deg[n], 1.0f);
            size_t idx = (size_t)n * FEAT + j;
            out[idx] = x[idx] + invd * acc;
        }
    }
}

extern "C" void kernel_launch(void* const* d_in, const int* in_sizes, int n_in,
                              void* d_out, int out_size, void* d_ws, size_t ws_size,
                              hipStream_t stream) {
    const float* x         = (const float*)d_in[0];
    const int*   ei        = (const int*)d_in[1];
    const float* edge_len  = (const float*)d_in[2];
    const float* W_mix     = (const float*)d_in[3];
    const float* log_scale = (const float*)d_in[4];
    const float* filter_w  = (const float*)d_in[5];
    const float* filter_b  = (const float*)d_in[6];
    float* out = (float*)d_out;

    const int N = in_sizes[0] / FEAT;
    const int E = in_sizes[1] / 2;
    const int* sender   = ei;
    const int* receiver = ei + E;
    const int nbuck = (N + BNODES - 1) >> BSHIFT;
    const int nchunk = (E + EPB - 1) / EPB;

    size_t xbf_bytes  = (size_t)N * FEAT * 2;
    size_t aggb_bytes = (size_t)N * FEAT * 2;
    size_t gcnt_bytes = (((size_t)nbuck * 4) + 63) & ~(size_t)63;
    size_t deg_bytes  = (((size_t)N * 4) + 63) & ~(size_t)63;

    // bucket region capacity: want 2*mean+512; shrink to fit; floor mean+5sigma
    int mean = E / nbuck + 1;
    size_t head = xbf_bytes + aggb_bytes + gcnt_bytes + deg_bytes;
    size_t avail = (ws_size > head) ? ws_size - head : 0;
    int cap = (2 * mean + 512 + 63) & ~63;
    int capmax = (int)((avail / ((size_t)nbuck * 8)) & ~(size_t)63);
    if (cap > capmax) cap = capmax;
    int sigma5 = 5 * (int)sqrtf((float)mean) + 64;
    bool ok = (N <= 65536) && (nbuck <= NBUCK_MAX) && (cap >= mean + sigma5);

    if (ok) {
        char* p = (char*)d_ws;
        uint2* xbf    = (uint2*)p;                        p += xbf_bytes;
        uint4* agg_bf = (uint4*)p;                        p += aggb_bytes;
        int* gcnt     = (int*)p;                          p += gcnt_bytes;
        int* deg      = (int*)p;                          p += deg_bytes;
        unsigned long long* buf = (unsigned long long*)p;

        (void)hipMemsetAsync(gcnt, 0, (size_t)nbuck * sizeof(int), stream);

        int n4 = N * (FEAT / 4);
        int cblocks = (n4 + 255) / 256;
        convert_scatter_kernel<<<nchunk + cblocks, 256, 0, stream>>>(
            (const float4*)x, xbf, n4, sender, receiver, edge_len,
            log_scale, filter_w, filter_b, gcnt, buf, E, nbuck, cap, nchunk);
        bucket_sort_aggregate_kernel<<<nbuck * 4, 256, 0, stream>>>(
            (const uint4*)xbf, buf, gcnt, agg_bf, deg, N, cap);
        int fblocks = (N + 63) / 64;
        finalize_kernel<<<fblocks, 256, 0, stream>>>(
            x, (const uint4*)agg_bf, deg, W_mix, out, N);
    } else {
        float* agg = (float*)d_ws;
        float* degf = agg + (size_t)N * FEAT;
        (void)hipMemsetAsync(agg, 0, ((size_t)N * FEAT + N) * sizeof(float), stream);
        int sblocks = (E * 32 + 255) / 256;
        scatter_fallback<<<sblocks, 256, 0, stream>>>(
            (const float4*)x, sender, receiver, edge_len,
            log_scale, filter_w, filter_b, agg, degf, E);
        finalize_fallback<<<512, 256, 0, stream>>>(x, agg, degf, W_mix, out, N);
    }
}

// Round 8
// 216.219 us; speedup vs baseline: 1.8194x; 1.0512x over previous
//
#include <hip/hip_runtime.h>
#include <math.h>

#define FEAT 128
#define BSHIFT 6            // 64 nodes per COARSE bucket
#define BNODES 64
#define CAP2 2048           // records per LDS sort chunk in K2 (16 KB)
#define NBUCK_MAX 1024      // N <= 65536 -> nbuck <= 1024 (fits 10 bits)
#define EPB 4096            // edges per scatter chunk: 367 blocks at E=1.5M

__device__ __forceinline__ float edge_weight(float d, float scale, float fw, float fb) {
    // scale already includes +1e-6
    float t = fmaxf(d / scale, 0.0f);
    float decay = expf(-t * t);
    float g = 1.0f / (1.0f + expf(-(d * fw + fb)));
    float w = decay * g;
    if (!isfinite(w)) w = 0.0f;
    return w;
}

__device__ __forceinline__ unsigned int bf16_rne(float f) {
    unsigned int b = __float_as_uint(f);
    return (b + 0x7FFFu + ((b >> 16) & 1u)) >> 16;
}

__device__ __forceinline__ void accum8(float acc[8], uint4 u, float w) {
    acc[0] = fmaf(w, __uint_as_float(u.x << 16), acc[0]);
    acc[1] = fmaf(w, __uint_as_float(u.x & 0xFFFF0000u), acc[1]);
    acc[2] = fmaf(w, __uint_as_float(u.y << 16), acc[2]);
    acc[3] = fmaf(w, __uint_as_float(u.y & 0xFFFF0000u), acc[3]);
    acc[4] = fmaf(w, __uint_as_float(u.z << 16), acc[4]);
    acc[5] = fmaf(w, __uint_as_float(u.z & 0xFFFF0000u), acc[5]);
    acc[6] = fmaf(w, __uint_as_float(u.w << 16), acc[6]);
    acc[7] = fmaf(w, __uint_as_float(u.w & 0xFFFF0000u), acc[7]);
}

// ==== K1: scatter chunks [0,nchunk) + convert blocks [nchunk,...).
// Scatter: LDS histogram -> LDS scan -> ONE global atomicAdd per bucket
// (reserve run) -> counting-sort records into LDS -> COALESCED writeout
// (consecutive threads hit consecutive slots of each bucket's run).
// Bucket id (10 bits) is stashed in record bits 22..31 for the writeout;
// K2 only reads bits 0..21 + weight, so the stash is harmless.
__global__ __launch_bounds__(256) void convert_scatter_kernel(
    const float4* __restrict__ x4, uint2* __restrict__ xbf, int n4,
    const int* __restrict__ sender, const int* __restrict__ recv,
    const float* __restrict__ edge_len,
    const float* __restrict__ log_scale, const float* __restrict__ filter_w,
    const float* __restrict__ filter_b,
    int* __restrict__ gcnt, unsigned long long* __restrict__ buf,
    int E, int nbuck, int cap, int nchunk) {
    __shared__ unsigned long long recS[EPB];   // 32 KB
    __shared__ int cnt[NBUCK_MAX];             // histogram
    __shared__ int segoff[NBUCK_MAX];          // local exclusive scan
    __shared__ int segcur[NBUCK_MAX];          // rank cursor
    __shared__ int resbase[NBUCK_MAX];         // global run base (abs position)
    __shared__ int part[256];
    const int tid = threadIdx.x;

    if ((int)blockIdx.x >= nchunk) {            // ---- convert part ----
        int i = ((int)blockIdx.x - nchunk) * 256 + tid;
        if (i >= n4) return;
        float4 v = x4[i];
        uint2 o;
        o.x = (bf16_rne(v.y) << 16) | bf16_rne(v.x);
        o.y = (bf16_rne(v.w) << 16) | bf16_rne(v.z);
        xbf[i] = o;
        return;
    }

    // ---- scatter part ----
    const int c = blockIdx.x;
    for (int i = tid; i < nbuck; i += 256) cnt[i] = 0;
    __syncthreads();
    const int base = c * EPB;
    const int end = min(base + EPB, E);
    const int cntE = end - base;
    for (int e = base + tid; e < end; e += 256)
        atomicAdd(&cnt[recv[e] >> BSHIFT], 1);
    __syncthreads();

    // local exclusive scan over nbuck (<=1024) entries: 4 per thread
    {
        int i0 = tid * 4;
        int v0 = 0, v1 = 0, v2 = 0, v3 = 0;
        if (i0 < nbuck) {
            v0 = cnt[i0];
            v1 = (i0 + 1 < nbuck) ? cnt[i0 + 1] : 0;
            v2 = (i0 + 2 < nbuck) ? cnt[i0 + 2] : 0;
            v3 = (i0 + 3 < nbuck) ? cnt[i0 + 3] : 0;
        }
        int s = v0 + v1 + v2 + v3;
        part[tid] = s;
        __syncthreads();
        for (int d = 1; d < 256; d <<= 1) {
            int t = (tid >= d) ? part[tid - d] : 0;
            __syncthreads();
            part[tid] += t;
            __syncthreads();
        }
        int run = part[tid] - s;
        if (i0 < nbuck) {
            segoff[i0] = run; run += v0;
            if (i0 + 1 < nbuck) { segoff[i0 + 1] = run; run += v1; }
            if (i0 + 2 < nbuck) { segoff[i0 + 2] = run; run += v2; }
            if (i0 + 3 < nbuck) { segoff[i0 + 3] = run; run += v3; }
        }
    }
    // reserve global runs + init cursors
    for (int i = tid; i < nbuck; i += 256) {
        int cc = cnt[i];
        int b0 = cc ? atomicAdd(&gcnt[i], cc) : 0;
        resbase[i] = i * cap + b0;
        segcur[i] = segoff[i];
    }
    __syncthreads();

    // build records sorted-by-bucket in LDS
    float scale = expf(log_scale[0]) + 1e-6f;
    float fw = filter_w[0], fb = filter_b[0];
    for (int e = base + tid; e < end; e += 256) {
        int r = recv[e];
        int s = sender[e];
        float w = edge_weight(edge_len[e], scale, fw, fb);
        int bk = r >> BSHIFT;
        int j = atomicAdd(&segcur[bk], 1);
        recS[j] = ((unsigned long long)__float_as_uint(w) << 32)
                | (unsigned int)(s & 0xFFFF)
                | ((unsigned int)(r & (BNODES - 1)) << 16)
                | ((unsigned int)(bk & 1023) << 22);
    }
    __syncthreads();

    // coalesced writeout: sorted slot j -> run position
    for (int j = tid; j < cntE; j += 256) {
        unsigned long long rec = recS[j];
        int bk = ((unsigned int)rec >> 22) & 1023;
        int pos = resbase[bk] + (j - segoff[bk]);
        if (pos < (bk + 1) * cap)   // safety only; cap >= mean+5sigma
            buf[pos] = rec;
    }
}

// ==== K2: single-pass sort+aggregate. One 512-thread block per coarse
// bucket; 32 groups x 2 nodes. Each record read+ranked ONCE (no 4x filter).
__global__ __launch_bounds__(512) void bucket_sort_aggregate_kernel(
    const uint4* __restrict__ xbf4, const unsigned long long* __restrict__ buf,
    const int* __restrict__ gcnt, uint4* __restrict__ agg_bf4,
    int* __restrict__ deg, int N, int cap) {
    __shared__ unsigned long long recS[CAP2];   // 16 KB
    __shared__ int cnt64[BNODES];
    __shared__ int segoff[BNODES + 1];

    const int b = blockIdx.x;
    const int n0 = b << BSHIFT;
    const int tid = threadIdx.x;
    const int lane = tid & 15;
    const int grp = tid >> 4;   // 0..31
    const int lo = b * cap;
    const int hi = lo + min(gcnt[b], cap);

    float acc[2][8] = {{0.f,0.f,0.f,0.f,0.f,0.f,0.f,0.f},
                       {0.f,0.f,0.f,0.f,0.f,0.f,0.f,0.f}};
    int dcnt[2] = {0, 0};

    for (int pos = lo; pos < hi; pos += CAP2) {
        int cnt = min(CAP2, hi - pos);
        if (tid < BNODES) cnt64[tid] = 0;
        __syncthreads();

        unsigned long long rec[CAP2 / 512];
        int rnk[CAP2 / 512];
        int locl[CAP2 / 512];
#pragma unroll
        for (int k = 0; k < CAP2 / 512; ++k) {
            int i = k * 512 + tid;
            rnk[k] = -1;
            if (i < cnt) {
                unsigned long long r = buf[pos + i];
                int l = ((unsigned int)r >> 16) & (BNODES - 1);
                rec[k] = r;
                locl[k] = l;
                rnk[k] = atomicAdd(&cnt64[l], 1);
            }
        }
        __syncthreads();
        if (tid == 0) {
            int run = 0;
#pragma unroll
            for (int l = 0; l < BNODES; ++l) { segoff[l] = run; run += cnt64[l]; }
            segoff[BNODES] = run;
        }
        __syncthreads();
#pragma unroll
        for (int k = 0; k < CAP2 / 512; ++k)
            if (rnk[k] >= 0) recS[segoff[locl[k]] + rnk[k]] = rec[k];
        __syncthreads();

#pragma unroll
        for (int which = 0; which < 2; ++which) {
            int l = grp + which * 32;
            int s0 = segoff[l], s1 = segoff[l + 1];
            dcnt[which] += s1 - s0;
            int i = s0;
            for (; i + 4 <= s1; i += 4) {
                unsigned long long r0 = recS[i];
                unsigned long long r1 = recS[i + 1];
                unsigned long long r2 = recS[i + 2];
                unsigned long long r3 = recS[i + 3];
                float w0 = __uint_as_float((unsigned int)(r0 >> 32));
                float w1 = __uint_as_float((unsigned int)(r1 >> 32));
                float w2 = __uint_as_float((unsigned int)(r2 >> 32));
                float w3 = __uint_as_float((unsigned int)(r3 >> 32));
                int s0i = (unsigned int)r0 & 0xFFFF;
                int s1i = (unsigned int)r1 & 0xFFFF;
                int s2i = (unsigned int)r2 & 0xFFFF;
                int s3i = (unsigned int)r3 & 0xFFFF;
                uint4 u0 = xbf4[(size_t)s0i * 16 + lane];
                uint4 u1 = xbf4[(size_t)s1i * 16 + lane];
                uint4 u2 = xbf4[(size_t)s2i * 16 + lane];
                uint4 u3 = xbf4[(size_t)s3i * 16 + lane];
                accum8(acc[which], u0, w0);
                accum8(acc[which], u1, w1);
                accum8(acc[which], u2, w2);
                accum8(acc[which], u3, w3);
            }
            for (; i < s1; ++i) {
                unsigned long long ra = recS[i];
                float wa = __uint_as_float((unsigned int)(ra >> 32));
                int sa = (unsigned int)ra & 0xFFFF;
                uint4 ua = xbf4[(size_t)sa * 16 + lane];
                accum8(acc[which], ua, wa);
            }
        }
        __syncthreads();   // before next chunk overwrites recS
    }

    // writeout: bf16-pack; lane owns features lane*8..lane*8+7
#pragma unroll
    for (int which = 0; which < 2; ++which) {
        int n = n0 + grp + which * 32;
        if (n < N) {
            uint4 o;
            o.x = (bf16_rne(acc[which][1]) << 16) | bf16_rne(acc[which][0]);
            o.y = (bf16_rne(acc[which][3]) << 16) | bf16_rne(acc[which][2]);
            o.z = (bf16_rne(acc[which][5]) << 16) | bf16_rne(acc[which][4]);
            o.w = (bf16_rne(acc[which][7]) << 16) | bf16_rne(acc[which][6]);
            agg_bf4[(size_t)n * 16 + lane] = o;
            if (lane == 0) deg[n] = dcnt[which];
        }
    }
}

// ---------------- finalize: tiled GEMM, out = x + (agg/deg) @ W --------------
__global__ __launch_bounds__(256) void finalize_kernel(
    const float* __restrict__ x, const uint4* __restrict__ agg_bf4,
    const int* __restrict__ deg, const float* __restrict__ Wm,
    float* __restrict__ out, int N) {
    __shared__ float aggS[64 * 128];  // 32 KB
    __shared__ float Ws[128 * 64];    // 32 KB
    const int n0 = blockIdx.x * 64;

    for (int i = threadIdx.x; i < 64 * 16; i += 256) {
        int r = i >> 4;
        int q = i & 15;
        int n = n0 + r;
        uint4 u = make_uint4(0u, 0u, 0u, 0u);
        if (n < N) u = agg_bf4[(size_t)n * 16 + q];
        float4 f0, f1;
        f0.x = __uint_as_float(u.x << 16);
        f0.y = __uint_as_float(u.x & 0xFFFF0000u);
        f0.z = __uint_as_float(u.y << 16);
        f0.w = __uint_as_float(u.y & 0xFFFF0000u);
        f1.x = __uint_as_float(u.z << 16);
        f1.y = __uint_as_float(u.z & 0xFFFF0000u);
        f1.z = __uint_as_float(u.w << 16);
        f1.w = __uint_as_float(u.w & 0xFFFF0000u);
        int m = (r >> 2) & 7;
        ((float4*)aggS)[r * 32 + ((2 * q) ^ m)] = f0;
        ((float4*)aggS)[r * 32 + ((2 * q + 1) ^ m)] = f1;
    }

    const int tc = threadIdx.x & 15;
    const int tr = threadIdx.x >> 4;

    float invd[4];
#pragma unroll
    for (int i = 0; i < 4; ++i) {
        int n = n0 + 4 * tr + i;
        float degf = 1.0f;
        if (n < N) degf = fmaxf((float)deg[n], 1.0f);
        invd[i] = 1.0f / degf;
    }

    for (int h = 0; h < 2; ++h) {
        for (int i = threadIdx.x; i < 128 * 16; i += 256) {
            int k = i >> 4;
            int j4 = i & 15;
            ((float4*)Ws)[k * 16 + j4] = ((const float4*)Wm)[k * 32 + h * 16 + j4];
        }
        __syncthreads();

        float acc[4][4];
#pragma unroll
        for (int i = 0; i < 4; ++i)
#pragma unroll
            for (int c = 0; c < 4; ++c) acc[i][c] = 0.f;

#pragma unroll 4
        for (int k0 = 0; k0 < 128; k0 += 4) {
            float4 ar4[4];
            const int chunk = (k0 >> 2) ^ (tr & 7);
#pragma unroll
            for (int i = 0; i < 4; ++i) {
                int r = 4 * tr + i;
                ar4[i] = ((const float4*)aggS)[r * 32 + chunk];
            }
            float4 wv4[4];
#pragma unroll
            for (int kk = 0; kk < 4; ++kk)
                wv4[kk] = *(const float4*)&Ws[(k0 + kk) * 64 + tc * 4];

            float wvv[4][4];
#pragma unroll
            for (int kk = 0; kk < 4; ++kk) {
                wvv[kk][0] = wv4[kk].x; wvv[kk][1] = wv4[kk].y;
                wvv[kk][2] = wv4[kk].z; wvv[kk][3] = wv4[kk].w;
            }
#pragma unroll
            for (int i = 0; i < 4; ++i) {
                float av[4] = {ar4[i].x, ar4[i].y, ar4[i].z, ar4[i].w};
#pragma unroll
                for (int kk = 0; kk < 4; ++kk)
#pragma unroll
                    for (int c = 0; c < 4; ++c)
                        acc[i][c] = fmaf(av[kk], wvv[kk][c], acc[i][c]);
            }
        }

#pragma unroll
        for (int i = 0; i < 4; ++i) {
            int n = n0 + 4 * tr + i;
            if (n < N) {
                size_t base = (size_t)n * FEAT + h * 64 + tc * 4;
                float4 xv = *(const float4*)&x[base];
                float4 o;
                o.x = xv.x + invd[i] * acc[i][0];
                o.y = xv.y + invd[i] * acc[i][1];
                o.z = xv.z + invd[i] * acc[i][2];
                o.w = xv.w + invd[i] * acc[i][3];
                *(float4*)&out[base] = o;
            }
        }
        __syncthreads();
    }
}

// ---------------- fallback (atomic path) ---------------
__global__ __launch_bounds__(256) void scatter_fallback(
    const float4* __restrict__ x4, const int* __restrict__ sender,
    const int* __restrict__ receiver, const float* __restrict__ edge_len,
    const float* __restrict__ log_scale, const float* __restrict__ filter_w,
    const float* __restrict__ filter_b, float* __restrict__ agg,
    float* __restrict__ deg, int E) {
    int gid = blockIdx.x * 256 + threadIdx.x;
    int e = gid >> 5;
    if (e >= E) return;
    int lane = gid & 31;
    int s = sender[e];
    int r = receiver[e];
    float scale = expf(log_scale[0]) + 1e-6f;
    float w = edge_weight(edge_len[e], scale, filter_w[0], filter_b[0]);
    float4 xv = x4[s * (FEAT / 4) + lane];
    float* dst = agg + (size_t)r * FEAT + lane * 4;
    unsafeAtomicAdd(dst + 0, w * xv.x);
    unsafeAtomicAdd(dst + 1, w * xv.y);
    unsafeAtomicAdd(dst + 2, w * xv.z);
    unsafeAtomicAdd(dst + 3, w * xv.w);
    if (lane == 0) unsafeAtomicAdd(&deg[r], 1.0f);
}

__global__ __launch_bounds__(256) void finalize_fallback(
    const float* __restrict__ x, const float* __restrict__ agg,
    const float* __restrict__ deg, const float* __restrict__ Wm,
    float* __restrict__ out, int N) {
    __shared__ float Wsf[FEAT * FEAT];
    for (int i = threadIdx.x * 4; i < FEAT * FEAT; i += 256 * 4)
        *(float4*)&Wsf[i] = *(const float4*)&Wm[i];
    __syncthreads();
    int half = threadIdx.x >> 7;
    int j = threadIdx.x & (FEAT - 1);
    for (int n0 = blockIdx.x * 2; n0 < N; n0 += gridDim.x * 2) {
        int n = n0 + half;
        if (n < N) {
            const float* arow = agg + (size_t)n * FEAT;
            float acc = 0.0f;
#pragma unroll 16
            for (int k = 0; k < FEAT; ++k) acc = fmaf(arow[k], Wsf[k * FEAT + j], acc);
            float invd = 1.0f / fmaxf(deg[n], 1.0f);
            size_t idx = (size_t)n * FEAT + j;
            out[idx] = x[idx] + invd * acc;
        }
    }
}

extern "C" void kernel_launch(void* const* d_in, const int* in_sizes, int n_in,
                              void* d_out, int out_size, void* d_ws, size_t ws_size,
                              hipStream_t stream) {
    const float* x         = (const float*)d_in[0];
    const int*   ei        = (const int*)d_in[1];
    const float* edge_len  = (const float*)d_in[2];
    const float* W_mix     = (const float*)d_in[3];
    const float* log_scale = (const float*)d_in[4];
    const float* filter_w  = (const float*)d_in[5];
    const float* filter_b  = (const float*)d_in[6];
    float* out = (float*)d_out;

    const int N = in_sizes[0] / FEAT;
    const int E = in_sizes[1] / 2;
    const int* sender   = ei;
    const int* receiver = ei + E;
    const int nbuck = (N + BNODES - 1) >> BSHIFT;
    const int nchunk = (E + EPB - 1) / EPB;

    size_t xbf_bytes  = (size_t)N * FEAT * 2;
    size_t aggb_bytes = (size_t)N * FEAT * 2;
    size_t gcnt_bytes = (((size_t)nbuck * 4) + 63) & ~(size_t)63;
    size_t deg_bytes  = (((size_t)N * 4) + 63) & ~(size_t)63;

    // bucket region capacity: want 2*mean+512; shrink to fit; floor mean+5sigma
    int mean = E / nbuck + 1;
    size_t head = xbf_bytes + aggb_bytes + gcnt_bytes + deg_bytes;
    size_t avail = (ws_size > head) ? ws_size - head : 0;
    int cap = (2 * mean + 512 + 63) & ~63;
    int capmax = (int)((avail / ((size_t)nbuck * 8)) & ~(size_t)63);
    if (cap > capmax) cap = capmax;
    int sigma5 = 5 * (int)sqrtf((float)mean) + 64;
    bool ok = (N <= 65536) && (nbuck <= NBUCK_MAX) && (cap >= mean + sigma5);

    if (ok) {
        char* p = (char*)d_ws;
        uint2* xbf    = (uint2*)p;                        p += xbf_bytes;
        uint4* agg_bf = (uint4*)p;                        p += aggb_bytes;
        int* gcnt     = (int*)p;                          p += gcnt_bytes;
        int* deg      = (int*)p;                          p += deg_bytes;
        unsigned long long* buf = (unsigned long long*)p;

        (void)hipMemsetAsync(gcnt, 0, (size_t)nbuck * sizeof(int), stream);

        int n4 = N * (FEAT / 4);
        int cblocks = (n4 + 255) / 256;
        convert_scatter_kernel<<<nchunk + cblocks, 256, 0, stream>>>(
            (const float4*)x, xbf, n4, sender, receiver, edge_len,
            log_scale, filter_w, filter_b, gcnt, buf, E, nbuck, cap, nchunk);
        bucket_sort_aggregate_kernel<<<nbuck, 512, 0, stream>>>(
            (const uint4*)xbf, buf, gcnt, agg_bf, deg, N, cap);
        int fblocks = (N + 63) / 64;
        finalize_kernel<<<fblocks, 256, 0, stream>>>(
            x, (const uint4*)agg_bf, deg, W_mix, out, N);
    } else {
        float* agg = (float*)d_ws;
        float* degf = agg + (size_t)N * FEAT;
        (void)hipMemsetAsync(agg, 0, ((size_t)N * FEAT + N) * sizeof(float), stream);
        int sblocks = (E * 32 + 255) / 256;
        scatter_fallback<<<sblocks, 256, 0, stream>>>(
            (const float4*)x, sender, receiver, edge_len,
            log_scale, filter_w, filter_b, agg, degf, E);
        finalize_fallback<<<512, 256, 0, stream>>>(x, agg, degf, W_mix, out, N);
    }
}